// Round 1
// baseline (241.739 us; speedup 1.0000x reference)
//
#include <hip/hip_runtime.h>

constexpr int NN = 10000;
constexpr int NE = 160000;
constexpr int D  = 512;
constexpr int EF = 80;   // RBF(64) + ANG(16)

// ---------------------------------------------------------------------------
// Scatter: aggF[row[e]][f] += edge_feat[e][f];  cnt[row[e]] += 1
// Algebraic trick: segment_sum(edge@W+b) == segment_sum(edge)@W + cnt*b
// ---------------------------------------------------------------------------
__global__ __launch_bounds__(256)
void scatter_kernel(const int* __restrict__ row,
                    const float* __restrict__ rbf,
                    const float* __restrict__ ang,
                    float* __restrict__ aggF,
                    float* __restrict__ cnt) {
    const long long total = (long long)NE * EF;
    for (long long t = (long long)blockIdx.x * blockDim.x + threadIdx.x;
         t < total; t += (long long)gridDim.x * blockDim.x) {
        int e = (int)(t / EF);
        int f = (int)(t - (long long)e * EF);
        float v = (f < 64) ? rbf[e * 64 + f] : ang[e * 16 + (f - 64)];
        int r = row[e];
        atomicAdd(&aggF[r * EF + f], v);
        if (f == 0) atomicAdd(&cnt[r], 1.0f);
    }
}

// ---------------------------------------------------------------------------
// fp32 tiled GEMM: C[M,512] = A[M,K] @ B[K,512] (+ epilogue)
//   MODE 0: C = A@B + extra[r] * bias[c]          (edge gemm: cnt * b_edge)
//   MODE 1: C = relu(A@B + bias[c])               (MLP layer 1)
//   MODE 2: C = A@B + bias[c] + extra[r*D+c]      (MLP layer 2 + residual x)
// 64x64 tile, BK=16, 256 threads, 4x4 micro-tile per thread.
// ---------------------------------------------------------------------------
template <int K, int MODE>
__global__ __launch_bounds__(256)
void gemm_kernel(const float* __restrict__ A,
                 const float* __restrict__ B,
                 const float* __restrict__ bias,
                 const float* __restrict__ extra,
                 float* __restrict__ C, int M) {
    __shared__ float As[16][64];
    __shared__ float Bs[16][64];
    const int tid = threadIdx.x;
    const int tx = tid & 15;        // col group (0..15) -> cols tx*4..+3
    const int ty = tid >> 4;        // row group (0..15) -> rows ty*4..+3
    const int n0 = blockIdx.x * 64;
    const int m0 = blockIdx.y * 64;

    float acc[4][4] = {};

    const int am  = tid >> 2;       // 0..63  (row within A tile)
    const int akg = tid & 3;        // 0..3   (k group of 4)
    const int bk  = tid >> 4;       // 0..15  (k row of B tile)
    const int bg  = tid & 15;       // 0..15  (col group of 4)

    for (int k0 = 0; k0 < K; k0 += 16) {
        float4 av;
        if (m0 + am < M) {
            av = *reinterpret_cast<const float4*>(&A[(long long)(m0 + am) * K + k0 + akg * 4]);
        } else {
            av = make_float4(0.f, 0.f, 0.f, 0.f);
        }
        float4 bv = *reinterpret_cast<const float4*>(&B[(long long)(k0 + bk) * D + n0 + bg * 4]);
        __syncthreads();   // protect previous iteration's reads
        As[akg * 4 + 0][am] = av.x;
        As[akg * 4 + 1][am] = av.y;
        As[akg * 4 + 2][am] = av.z;
        As[akg * 4 + 3][am] = av.w;
        *reinterpret_cast<float4*>(&Bs[bk][bg * 4]) = bv;
        __syncthreads();
        #pragma unroll
        for (int k = 0; k < 16; ++k) {
            float4 a = *reinterpret_cast<const float4*>(&As[k][ty * 4]);
            float4 b = *reinterpret_cast<const float4*>(&Bs[k][tx * 4]);
            float ar[4] = {a.x, a.y, a.z, a.w};
            float br[4] = {b.x, b.y, b.z, b.w};
            #pragma unroll
            for (int i = 0; i < 4; ++i)
                #pragma unroll
                for (int j = 0; j < 4; ++j)
                    acc[i][j] = fmaf(ar[i], br[j], acc[i][j]);
        }
    }

    #pragma unroll
    for (int i = 0; i < 4; ++i) {
        int r = m0 + ty * 4 + i;
        if (r >= M) break;
        #pragma unroll
        for (int j = 0; j < 4; ++j) {
            int c = n0 + tx * 4 + j;
            float v = acc[i][j];
            if (MODE == 0)      v += extra[r] * bias[c];
            else if (MODE == 1) { v += bias[c]; v = fmaxf(v, 0.f); }
            else                v += bias[c] + extra[(long long)r * D + c];
            C[(long long)r * D + c] = v;
        }
    }
}

extern "C" void kernel_launch(void* const* d_in, const int* in_sizes, int n_in,
                              void* d_out, int out_size, void* d_ws, size_t ws_size,
                              hipStream_t stream) {
    const float* x      = (const float*)d_in[0];
    // d_in[1] = coord (unused by reference)
    const int*   edge_index = (const int*)d_in[2];   // [2, NE]; row = first NE
    const float* rbf    = (const float*)d_in[3];
    const float* ang    = (const float*)d_in[4];
    const float* W_edge = (const float*)d_in[5];
    const float* b_edge = (const float*)d_in[6];
    const float* W1     = (const float*)d_in[7];
    const float* b1     = (const float*)d_in[8];
    const float* W2     = (const float*)d_in[9];
    const float* b2     = (const float*)d_in[10];
    float* out = (float*)d_out;

    float* ws   = (float*)d_ws;
    float* aggF = ws;                               // NN*EF
    float* cnt  = ws + (size_t)NN * EF;             // NN
    float* agg  = cnt + NN;                         // NN*D  (16B-aligned: 810000*4)
    float* h1   = agg + (size_t)NN * D;             // NN*D

    hipMemsetAsync(ws, 0, (size_t)(NN * EF + NN) * sizeof(float), stream);

    scatter_kernel<<<4096, 256, 0, stream>>>(edge_index, rbf, ang, aggF, cnt);

    dim3 grid(D / 64, (NN + 63) / 64);
    gemm_kernel<EF, 0><<<grid, 256, 0, stream>>>(aggF, W_edge, b_edge, cnt, agg, NN);
    gemm_kernel<D, 1><<<grid, 256, 0, stream>>>(agg, W1, b1, nullptr, h1, NN);
    gemm_kernel<D, 2><<<grid, 256, 0, stream>>>(h1, W2, b2, x, out, NN);
}

// Round 2
// 164.670 us; speedup vs baseline: 1.4680x; 1.4680x over previous
//
#include <hip/hip_runtime.h>

constexpr int NN = 10000;
constexpr int NE = 160000;
constexpr int D  = 512;
constexpr int EF = 80;   // RBF(64) + ANG(16)

typedef __attribute__((ext_vector_type(8))) short short8;   // 8 bf16 (4 VGPRs)
typedef __attribute__((ext_vector_type(4))) float f32x4;    // MFMA C/D

static __device__ __forceinline__ ushort f2bf(float f) {
    union { float f; unsigned u; } v; v.f = f;
    unsigned r = (v.u + 0x7FFFu + ((v.u >> 16) & 1u)) >> 16;   // RNE
    return (ushort)r;
}

// ---------------------------------------------------------------------------
// Scatter: aggF[row[e]][f] += edge_feat[e][f];  cnt[row[e]] += 1
// segment_sum(edge@W+b) == segment_sum(edge)@W + cnt*b
// ---------------------------------------------------------------------------
__global__ __launch_bounds__(256)
void scatter_kernel(const int* __restrict__ row,
                    const float* __restrict__ rbf,
                    const float* __restrict__ ang,
                    float* __restrict__ aggF,
                    float* __restrict__ cnt) {
    const long long total = (long long)NE * EF;
    for (long long t = (long long)blockIdx.x * blockDim.x + threadIdx.x;
         t < total; t += (long long)gridDim.x * blockDim.x) {
        int e = (int)(t / EF);
        int f = (int)(t - (long long)e * EF);
        float v = (f < 64) ? rbf[e * 64 + f] : ang[e * 16 + (f - 64)];
        int r = row[e];
        atomicAdd(&aggF[r * EF + f], v);
        if (f == 0) atomicAdd(&cnt[r], 1.0f);
    }
}

// ---------------------------------------------------------------------------
// Edge GEMM (fp32, K=80): agg_bf16[M,512] = bf16(aggF @ W_edge + cnt*b_edge)
// ---------------------------------------------------------------------------
__global__ __launch_bounds__(256)
void edge_gemm_kernel(const float* __restrict__ A,     // aggF [M][80]
                      const float* __restrict__ B,     // W_edge [80][512]
                      const float* __restrict__ bias,  // b_edge [512]
                      const float* __restrict__ cnt,   // [M]
                      ushort* __restrict__ C, int M) {
    __shared__ float As[16][64];
    __shared__ float Bs[16][64];
    const int tid = threadIdx.x;
    const int tx = tid & 15;
    const int ty = tid >> 4;
    const int n0 = blockIdx.x * 64;
    const int m0 = blockIdx.y * 64;

    float acc[4][4] = {};
    const int am  = tid >> 2;
    const int akg = tid & 3;
    const int bk  = tid >> 4;
    const int bg  = tid & 15;

    for (int k0 = 0; k0 < EF; k0 += 16) {
        float4 av;
        if (m0 + am < M) {
            av = *reinterpret_cast<const float4*>(&A[(long long)(m0 + am) * EF + k0 + akg * 4]);
        } else {
            av = make_float4(0.f, 0.f, 0.f, 0.f);
        }
        float4 bv = *reinterpret_cast<const float4*>(&B[(long long)(k0 + bk) * D + n0 + bg * 4]);
        __syncthreads();
        As[akg * 4 + 0][am] = av.x;
        As[akg * 4 + 1][am] = av.y;
        As[akg * 4 + 2][am] = av.z;
        As[akg * 4 + 3][am] = av.w;
        *reinterpret_cast<float4*>(&Bs[bk][bg * 4]) = bv;
        __syncthreads();
        #pragma unroll
        for (int k = 0; k < 16; ++k) {
            float4 a = *reinterpret_cast<const float4*>(&As[k][ty * 4]);
            float4 b = *reinterpret_cast<const float4*>(&Bs[k][tx * 4]);
            float ar[4] = {a.x, a.y, a.z, a.w};
            float br[4] = {b.x, b.y, b.z, b.w};
            #pragma unroll
            for (int i = 0; i < 4; ++i)
                #pragma unroll
                for (int j = 0; j < 4; ++j)
                    acc[i][j] = fmaf(ar[i], br[j], acc[i][j]);
        }
    }
    #pragma unroll
    for (int i = 0; i < 4; ++i) {
        int r = m0 + ty * 4 + i;
        if (r >= M) break;
        float cv = cnt[r];
        #pragma unroll
        for (int j = 0; j < 4; ++j) {
            int c = n0 + tx * 4 + j;
            C[(long long)r * D + c] = f2bf(acc[i][j] + cv * bias[c]);
        }
    }
}

// ---------------------------------------------------------------------------
// W [512][512] f32  ->  Wt [n][k] bf16 (transposed)
// ---------------------------------------------------------------------------
__global__ __launch_bounds__(256)
void transpose_bf16_kernel(const float* __restrict__ W, ushort* __restrict__ Wt) {
    __shared__ float tile[32][33];
    const int bx = blockIdx.x * 32;   // col block (n)
    const int by = blockIdx.y * 32;   // row block (k)
    const int tx = threadIdx.x & 31;
    const int ty = threadIdx.x >> 5;  // 0..7
    #pragma unroll
    for (int i = 0; i < 4; ++i)
        tile[ty + 8 * i][tx] = W[(size_t)(by + ty + 8 * i) * D + bx + tx];
    __syncthreads();
    #pragma unroll
    for (int i = 0; i < 4; ++i)
        Wt[(size_t)(bx + ty + 8 * i) * D + by + tx] = f2bf(tile[tx][ty + 8 * i]);
}

// ---------------------------------------------------------------------------
// MFMA bf16 GEMM: C[M,512] = A[M,512] @ Bt^T  (Bt is [n][k] bf16)
//   MODE 1: h1 = bf16(relu(acc + b1))      -> ushort out
//   MODE 2: out = acc + b2 + x             -> float out
// 128x128 tile, BK=64, 4 waves (2x2), 4x4 frags of 16x16x32 per wave.
// LDS rows padded to 72 bf16 (144B stride -> 2-way bank aliasing, free).
// ---------------------------------------------------------------------------
template <int MODE>
__global__ __launch_bounds__(256)
void mfma_gemm_kernel(const ushort* __restrict__ A,    // [M][512] bf16
                      const ushort* __restrict__ Bt,   // [512][512] bf16, [n][k]
                      const float* __restrict__ bias,  // [512]
                      const float* __restrict__ xres,  // [M][512] (MODE 2)
                      void* __restrict__ Cout, int M) {
    __shared__ ushort As[128 * 72];
    __shared__ ushort Bs[128 * 72];
    const int tid  = threadIdx.x;
    const int lane = tid & 63;
    const int wid  = tid >> 6;
    const int wm   = wid >> 1;        // 0..1
    const int wn   = wid & 1;         // 0..1
    const int n0 = blockIdx.x * 128;
    const int m0 = blockIdx.y * 128;

    f32x4 acc[4][4] = {};

    const int r0 = tid >> 3;          // 0..31 (staging row base)
    const int k8 = tid & 7;           // 16B chunk within 64-elem K row

    uint4 aReg[4], bReg[4];
    constexpr int KTILES = D / 64;

    // prefetch tile 0
    #pragma unroll
    for (int p = 0; p < 4; ++p) {
        int row = p * 32 + r0;
        int gm = m0 + row;
        aReg[p] = (gm < M)
            ? reinterpret_cast<const uint4*>(A + (size_t)gm * D)[k8]
            : make_uint4(0u, 0u, 0u, 0u);
        bReg[p] = reinterpret_cast<const uint4*>(Bt + (size_t)(n0 + row) * D)[k8];
    }

    for (int t = 0; t < KTILES; ++t) {
        #pragma unroll
        for (int p = 0; p < 4; ++p) {
            int row = p * 32 + r0;
            *reinterpret_cast<uint4*>(&As[row * 72 + k8 * 8]) = aReg[p];
            *reinterpret_cast<uint4*>(&Bs[row * 72 + k8 * 8]) = bReg[p];
        }
        __syncthreads();
        if (t + 1 < KTILES) {
            const int k0 = (t + 1) * 64;
            #pragma unroll
            for (int p = 0; p < 4; ++p) {
                int row = p * 32 + r0;
                int gm = m0 + row;
                aReg[p] = (gm < M)
                    ? reinterpret_cast<const uint4*>(A + (size_t)gm * D + k0)[k8]
                    : make_uint4(0u, 0u, 0u, 0u);
                bReg[p] = reinterpret_cast<const uint4*>(Bt + (size_t)(n0 + row) * D + k0)[k8];
            }
        }
        #pragma unroll
        for (int kk = 0; kk < 2; ++kk) {
            short8 af[4], bfr[4];
            const int klo = kk * 32 + (lane >> 4) * 8;
            #pragma unroll
            for (int mf = 0; mf < 4; ++mf) {
                int arow = wm * 64 + mf * 16 + (lane & 15);
                af[mf] = *reinterpret_cast<const short8*>(&As[arow * 72 + klo]);
            }
            #pragma unroll
            for (int nf = 0; nf < 4; ++nf) {
                int brow = wn * 64 + nf * 16 + (lane & 15);
                bfr[nf] = *reinterpret_cast<const short8*>(&Bs[brow * 72 + klo]);
            }
            #pragma unroll
            for (int mf = 0; mf < 4; ++mf)
                #pragma unroll
                for (int nf = 0; nf < 4; ++nf)
                    acc[mf][nf] = __builtin_amdgcn_mfma_f32_16x16x32_bf16(
                        af[mf], bfr[nf], acc[mf][nf], 0, 0, 0);
        }
        __syncthreads();
    }

    // epilogue: C/D layout col = lane&15, row = (lane>>4)*4 + reg  [m89]
    float*  outf = (float*)Cout;
    ushort* outh = (ushort*)Cout;
    #pragma unroll
    for (int mf = 0; mf < 4; ++mf) {
        const int rowb = m0 + wm * 64 + mf * 16 + ((lane >> 4) << 2);
        #pragma unroll
        for (int nf = 0; nf < 4; ++nf) {
            const int col = n0 + wn * 64 + nf * 16 + (lane & 15);
            const float bv = bias[col];
            #pragma unroll
            for (int r = 0; r < 4; ++r) {
                const int row = rowb + r;
                if (row < M) {
                    float v = acc[mf][nf][r] + bv;
                    if (MODE == 1) {
                        outh[(size_t)row * D + col] = f2bf(fmaxf(v, 0.f));
                    } else {
                        outf[(size_t)row * D + col] = v + xres[(size_t)row * D + col];
                    }
                }
            }
        }
    }
}

extern "C" void kernel_launch(void* const* d_in, const int* in_sizes, int n_in,
                              void* d_out, int out_size, void* d_ws, size_t ws_size,
                              hipStream_t stream) {
    const float* x      = (const float*)d_in[0];
    const int*   edge_index = (const int*)d_in[2];
    const float* rbf    = (const float*)d_in[3];
    const float* ang    = (const float*)d_in[4];
    const float* W_edge = (const float*)d_in[5];
    const float* b_edge = (const float*)d_in[6];
    const float* W1     = (const float*)d_in[7];
    const float* b1     = (const float*)d_in[8];
    const float* W2     = (const float*)d_in[9];
    const float* b2     = (const float*)d_in[10];
    float* out = (float*)d_out;

    char* w = (char*)d_ws;
    float*  aggF = (float*)w;                        //  3,200,000 B
    float*  cnt  = (float*)(w + 3200000);            //     40,000 B
    ushort* agg  = (ushort*)(w + 3240000);           // 10,240,000 B (bf16)
    ushort* h1   = (ushort*)(w + 13480000);          // 10,240,000 B (bf16)
    ushort* W1t  = (ushort*)(w + 23720000);          //    524,288 B
    ushort* W2t  = (ushort*)(w + 24244288);          //    524,288 B

    hipMemsetAsync(w, 0, 3240000, stream);

    scatter_kernel<<<4096, 256, 0, stream>>>(edge_index, rbf, ang, aggF, cnt);

    dim3 tgrid(D / 32, D / 32);
    transpose_bf16_kernel<<<tgrid, 256, 0, stream>>>(W1, W1t);
    transpose_bf16_kernel<<<tgrid, 256, 0, stream>>>(W2, W2t);

    dim3 egrid(D / 64, (NN + 63) / 64);
    edge_gemm_kernel<<<egrid, 256, 0, stream>>>(aggF, W_edge, b_edge, cnt, agg, NN);

    dim3 ggrid(D / 128, (NN + 127) / 128);
    mfma_gemm_kernel<1><<<ggrid, 256, 0, stream>>>(agg, W1t, b1, nullptr, h1, NN);
    mfma_gemm_kernel<2><<<ggrid, 256, 0, stream>>>(h1, W2t, b2, x, out, NN);
}

// Round 3
// 149.453 us; speedup vs baseline: 1.6175x; 1.1018x over previous
//
#include <hip/hip_runtime.h>

constexpr int NN = 10000;
constexpr int NE = 160000;
constexpr int D  = 512;
constexpr int EF = 80;   // RBF(64) + ANG(16)

typedef __attribute__((ext_vector_type(8))) short short8;   // 8 bf16 (4 VGPRs)
typedef __attribute__((ext_vector_type(4))) float f32x4;    // MFMA C/D

static __device__ __forceinline__ ushort f2bf(float f) {
    union { float f; unsigned u; } v; v.f = f;
    unsigned r = (v.u + 0x7FFFu + ((v.u >> 16) & 1u)) >> 16;   // RNE
    return (ushort)r;
}

// ---------------------------------------------------------------------------
// Scatter: aggF[row[e]][f] += edge_feat[e][f];  cnt[row[e]] += 1
// segment_sum(edge@W+b) == segment_sum(edge)@W + cnt*b
// ---------------------------------------------------------------------------
__global__ __launch_bounds__(256)
void scatter_kernel(const int* __restrict__ row,
                    const float* __restrict__ rbf,
                    const float* __restrict__ ang,
                    float* __restrict__ aggF,
                    float* __restrict__ cnt) {
    const long long total = (long long)NE * EF;
    for (long long t = (long long)blockIdx.x * blockDim.x + threadIdx.x;
         t < total; t += (long long)gridDim.x * blockDim.x) {
        int e = (int)(t / EF);
        int f = (int)(t - (long long)e * EF);
        float v = (f < 64) ? rbf[e * 64 + f] : ang[e * 16 + (f - 64)];
        int r = row[e];
        atomicAdd(&aggF[r * EF + f], v);
        if (f == 0) atomicAdd(&cnt[r], 1.0f);
    }
}

// ---------------------------------------------------------------------------
// Edge GEMM (fp32, K=80): agg_bf16[M,512] = bf16(aggF @ W_edge + cnt*b_edge)
// ---------------------------------------------------------------------------
__global__ __launch_bounds__(256)
void edge_gemm_kernel(const float* __restrict__ A,     // aggF [M][80]
                      const float* __restrict__ B,     // W_edge [80][512]
                      const float* __restrict__ bias,  // b_edge [512]
                      const float* __restrict__ cnt,   // [M]
                      ushort* __restrict__ C, int M) {
    __shared__ float As[16][64];
    __shared__ float Bs[16][64];
    const int tid = threadIdx.x;
    const int tx = tid & 15;
    const int ty = tid >> 4;
    const int n0 = blockIdx.x * 64;
    const int m0 = blockIdx.y * 64;

    float acc[4][4] = {};
    const int am  = tid >> 2;
    const int akg = tid & 3;
    const int bk  = tid >> 4;
    const int bg  = tid & 15;

    for (int k0 = 0; k0 < EF; k0 += 16) {
        float4 av;
        if (m0 + am < M) {
            av = *reinterpret_cast<const float4*>(&A[(long long)(m0 + am) * EF + k0 + akg * 4]);
        } else {
            av = make_float4(0.f, 0.f, 0.f, 0.f);
        }
        float4 bv = *reinterpret_cast<const float4*>(&B[(long long)(k0 + bk) * D + n0 + bg * 4]);
        __syncthreads();
        As[akg * 4 + 0][am] = av.x;
        As[akg * 4 + 1][am] = av.y;
        As[akg * 4 + 2][am] = av.z;
        As[akg * 4 + 3][am] = av.w;
        *reinterpret_cast<float4*>(&Bs[bk][bg * 4]) = bv;
        __syncthreads();
        #pragma unroll
        for (int k = 0; k < 16; ++k) {
            float4 a = *reinterpret_cast<const float4*>(&As[k][ty * 4]);
            float4 b = *reinterpret_cast<const float4*>(&Bs[k][tx * 4]);
            float ar[4] = {a.x, a.y, a.z, a.w};
            float br[4] = {b.x, b.y, b.z, b.w};
            #pragma unroll
            for (int i = 0; i < 4; ++i)
                #pragma unroll
                for (int j = 0; j < 4; ++j)
                    acc[i][j] = fmaf(ar[i], br[j], acc[i][j]);
        }
    }
    #pragma unroll
    for (int i = 0; i < 4; ++i) {
        int r = m0 + ty * 4 + i;
        if (r >= M) break;
        float cv = cnt[r];
        #pragma unroll
        for (int j = 0; j < 4; ++j) {
            int c = n0 + tx * 4 + j;
            C[(long long)r * D + c] = f2bf(acc[i][j] + cv * bias[c]);
        }
    }
}

// ---------------------------------------------------------------------------
// W [512][512] f32  ->  Wt [n][k] bf16 (transposed)
// ---------------------------------------------------------------------------
__global__ __launch_bounds__(256)
void transpose_bf16_kernel(const float* __restrict__ W, ushort* __restrict__ Wt) {
    __shared__ float tile[32][33];
    const int bx = blockIdx.x * 32;   // col block (n)
    const int by = blockIdx.y * 32;   // row block (k)
    const int tx = threadIdx.x & 31;
    const int ty = threadIdx.x >> 5;  // 0..7
    #pragma unroll
    for (int i = 0; i < 4; ++i)
        tile[ty + 8 * i][tx] = W[(size_t)(by + ty + 8 * i) * D + bx + tx];
    __syncthreads();
    #pragma unroll
    for (int i = 0; i < 4; ++i)
        Wt[(size_t)(bx + ty + 8 * i) * D + by + tx] = f2bf(tile[tx][ty + 8 * i]);
}

// ---------------------------------------------------------------------------
// MFMA bf16 GEMM: C[M,512] = A[M,512] @ Bt^T  (Bt is [n][k] bf16)
//   MODE 1: h1 = bf16(relu(acc + b1))      -> ushort out
//   MODE 2: out = acc + b2 + x             -> float out
// 64x64 tile, BK=64, 4 waves (2x2), each wave 32x32 via 2x2 16x16x32 frags.
// Grid = 8 x 157 = 1256 blocks (~4.9/CU) -- occupancy is the R2 fix.
// LDS rows padded to 72 bf16 (144B stride -> 2-way bank aliasing, free).
// XCD swizzle: each XCD gets a contiguous M-chunk (A-chunk 1.3MB + B 0.5MB
// L2-resident). nwg = 1256, 1256 % 8 == 0 -> simple bijective form valid.
// ---------------------------------------------------------------------------
template <int MODE>
__global__ __launch_bounds__(256)
void mfma_gemm_kernel(const ushort* __restrict__ A,    // [M][512] bf16
                      const ushort* __restrict__ Bt,   // [512][512] bf16, [n][k]
                      const float* __restrict__ bias,  // [512]
                      const float* __restrict__ xres,  // [M][512] (MODE 2)
                      void* __restrict__ Cout, int M) {
    __shared__ ushort As[64 * 72];
    __shared__ ushort Bs[64 * 72];
    const int tid  = threadIdx.x;
    const int lane = tid & 63;
    const int wid  = tid >> 6;
    const int wm   = wid >> 1;        // 0..1
    const int wn   = wid & 1;         // 0..1

    // XCD-aware swizzle: linear id l (hw XCD = l % 8) -> tile (l%8)*157 + l/8,
    // decoded as n = t % 8, m = t / 8  ==> XCD k owns a contiguous m-chunk.
    const int l = blockIdx.y * gridDim.x + blockIdx.x;
    const int nwg = gridDim.x * gridDim.y;
    const int cpx = nwg >> 3;                  // 157
    const int t_ = (l & 7) * cpx + (l >> 3);
    const int n0 = (t_ & 7) * 64;
    const int m0 = (t_ >> 3) * 64;

    f32x4 acc[2][2] = {};

    const int r0 = tid >> 3;          // 0..31 (staging row base)
    const int k8 = tid & 7;           // 16B chunk within 64-elem K row

    uint4 aReg[2], bReg[2];
    constexpr int KTILES = D / 64;

    // prefetch tile 0
    #pragma unroll
    for (int p = 0; p < 2; ++p) {
        int row = p * 32 + r0;
        int gm = m0 + row;
        aReg[p] = (gm < M)
            ? reinterpret_cast<const uint4*>(A + (size_t)gm * D)[k8]
            : make_uint4(0u, 0u, 0u, 0u);
        bReg[p] = reinterpret_cast<const uint4*>(Bt + (size_t)(n0 + row) * D)[k8];
    }

    for (int t = 0; t < KTILES; ++t) {
        #pragma unroll
        for (int p = 0; p < 2; ++p) {
            int row = p * 32 + r0;
            *reinterpret_cast<uint4*>(&As[row * 72 + k8 * 8]) = aReg[p];
            *reinterpret_cast<uint4*>(&Bs[row * 72 + k8 * 8]) = bReg[p];
        }
        __syncthreads();
        if (t + 1 < KTILES) {
            const int k0 = (t + 1) * 64;
            #pragma unroll
            for (int p = 0; p < 2; ++p) {
                int row = p * 32 + r0;
                int gm = m0 + row;
                aReg[p] = (gm < M)
                    ? reinterpret_cast<const uint4*>(A + (size_t)gm * D + k0)[k8]
                    : make_uint4(0u, 0u, 0u, 0u);
                bReg[p] = reinterpret_cast<const uint4*>(Bt + (size_t)(n0 + row) * D + k0)[k8];
            }
        }
        #pragma unroll
        for (int kk = 0; kk < 2; ++kk) {
            short8 af[2], bfr[2];
            const int klo = kk * 32 + (lane >> 4) * 8;
            #pragma unroll
            for (int mf = 0; mf < 2; ++mf) {
                int arow = wm * 32 + mf * 16 + (lane & 15);
                af[mf] = *reinterpret_cast<const short8*>(&As[arow * 72 + klo]);
            }
            #pragma unroll
            for (int nf = 0; nf < 2; ++nf) {
                int brow = wn * 32 + nf * 16 + (lane & 15);
                bfr[nf] = *reinterpret_cast<const short8*>(&Bs[brow * 72 + klo]);
            }
            #pragma unroll
            for (int mf = 0; mf < 2; ++mf)
                #pragma unroll
                for (int nf = 0; nf < 2; ++nf)
                    acc[mf][nf] = __builtin_amdgcn_mfma_f32_16x16x32_bf16(
                        af[mf], bfr[nf], acc[mf][nf], 0, 0, 0);
        }
        __syncthreads();
    }

    // epilogue: C/D layout col = lane&15, row = (lane>>4)*4 + reg  [m89]
    float*  outf = (float*)Cout;
    ushort* outh = (ushort*)Cout;
    #pragma unroll
    for (int mf = 0; mf < 2; ++mf) {
        const int rowb = m0 + wm * 32 + mf * 16 + ((lane >> 4) << 2);
        #pragma unroll
        for (int nf = 0; nf < 2; ++nf) {
            const int col = n0 + wn * 32 + nf * 16 + (lane & 15);
            const float bv = bias[col];
            #pragma unroll
            for (int r = 0; r < 4; ++r) {
                const int row = rowb + r;
                if (row < M) {
                    float v = acc[mf][nf][r] + bv;
                    if (MODE == 1) {
                        outh[(size_t)row * D + col] = f2bf(fmaxf(v, 0.f));
                    } else {
                        outf[(size_t)row * D + col] = v + xres[(size_t)row * D + col];
                    }
                }
            }
        }
    }
}

extern "C" void kernel_launch(void* const* d_in, const int* in_sizes, int n_in,
                              void* d_out, int out_size, void* d_ws, size_t ws_size,
                              hipStream_t stream) {
    const float* x      = (const float*)d_in[0];
    const int*   edge_index = (const int*)d_in[2];
    const float* rbf    = (const float*)d_in[3];
    const float* ang    = (const float*)d_in[4];
    const float* W_edge = (const float*)d_in[5];
    const float* b_edge = (const float*)d_in[6];
    const float* W1     = (const float*)d_in[7];
    const float* b1     = (const float*)d_in[8];
    const float* W2     = (const float*)d_in[9];
    const float* b2     = (const float*)d_in[10];
    float* out = (float*)d_out;

    char* w = (char*)d_ws;
    float*  aggF = (float*)w;                        //  3,200,000 B
    float*  cnt  = (float*)(w + 3200000);            //     40,000 B
    ushort* agg  = (ushort*)(w + 3240000);           // 10,240,000 B (bf16)
    ushort* h1   = (ushort*)(w + 13480000);          // 10,240,000 B (bf16)
    ushort* W1t  = (ushort*)(w + 23720000);          //    524,288 B
    ushort* W2t  = (ushort*)(w + 24244288);          //    524,288 B

    hipMemsetAsync(w, 0, 3240000, stream);

    scatter_kernel<<<4096, 256, 0, stream>>>(edge_index, rbf, ang, aggF, cnt);

    dim3 tgrid(D / 32, D / 32);
    transpose_bf16_kernel<<<tgrid, 256, 0, stream>>>(W1, W1t);
    transpose_bf16_kernel<<<tgrid, 256, 0, stream>>>(W2, W2t);

    dim3 egrid(D / 64, (NN + 63) / 64);
    edge_gemm_kernel<<<egrid, 256, 0, stream>>>(aggF, W_edge, b_edge, cnt, agg, NN);

    dim3 ggrid(D / 64, (NN + 63) / 64);   // 8 x 157 = 1256 blocks
    mfma_gemm_kernel<1><<<ggrid, 256, 0, stream>>>(agg, W1t, b1, nullptr, h1, NN);
    mfma_gemm_kernel<2><<<ggrid, 256, 0, stream>>>(h1, W2t, b2, x, out, NN);
}